// Round 10
// baseline (699.956 us; speedup 1.0000x reference)
//
#include <hip/hip_runtime.h>
#include <hip/hip_cooperative_groups.h>

namespace cg = cooperative_groups;

#define B_ 2
#define N_ 2048
#define E_ 64
#define FIN_ 18
#define ADJ_CAP 128
#define A2_CAP 1024
#define DR 16  // rows per block in dense kernels

__device__ __forceinline__ float wave_sum(float v) {
  #pragma unroll
  for (int o = 32; o > 0; o >>= 1) v += __shfl_xor(v, o);
  return v;
}
__device__ __forceinline__ float wave_max(float v) {
  #pragma unroll
  for (int o = 32; o > 0; o >>= 1) v = fmaxf(v, __shfl_xor(v, o));
  return v;
}
__device__ __forceinline__ void grp_reduce(float4& a) {
  #pragma unroll
  for (int o = 16; o <= 32; o <<= 1) {
    a.x += __shfl_xor(a.x, o); a.y += __shfl_xor(a.y, o);
    a.z += __shfl_xor(a.z, o); a.w += __shfl_xor(a.w, o);
  }
}

// ------- adj-only CSR scan + per-row 2048-bit adjacency bitmask; zero accum/tcnt ----
__global__ void k_csr_adj(const float* __restrict__ nbhd, int* __restrict__ adj_idx,
                          int* __restrict__ adj_cnt, unsigned* __restrict__ amask,
                          float* __restrict__ accum, int* __restrict__ tcnt) {
  int wv = threadIdx.x >> 6;
  int row = blockIdx.x * 4 + wv;  // 0..B*N-1
  int lane = threadIdx.x & 63;
  if (row == 0 && lane < 8) accum[lane] = 0.f;
  if (lane == 0) tcnt[row] = 0;
  __shared__ unsigned M[4][64];
  M[wv][lane] = 0;  // same-wave use only
  const float* r = nbhd + (size_t)row * N_;
  int* idx = adj_idx + (size_t)row * ADJ_CAP;
  int cnt = 0;
  unsigned long long below = (1ull << lane) - 1ull;
  for (int j0 = 0; j0 < N_; j0 += 256) {
    float4 v = ((const float4*)(r + j0))[lane];
    bool p0 = v.x > 0.f, p1 = v.y > 0.f, p2 = v.z > 0.f, p3 = v.w > 0.f;
    unsigned long long b0 = __ballot(p0), b1 = __ballot(p1),
                       b2 = __ballot(p2), b3 = __ballot(p3);
    int pos = cnt + __popcll(b0 & below) + __popcll(b1 & below) +
              __popcll(b2 & below) + __popcll(b3 & below);
    int base_j = j0 + lane * 4;
    if (p0) { if (pos < ADJ_CAP) idx[pos] = base_j;     pos++; }
    if (p1) { if (pos < ADJ_CAP) idx[pos] = base_j + 1; pos++; }
    if (p2) { if (pos < ADJ_CAP) idx[pos] = base_j + 2; pos++; }
    if (p3) { if (pos < ADJ_CAP) idx[pos] = base_j + 3; pos++; }
    unsigned nib = (p0 ? 1u : 0u) | (p1 ? 2u : 0u) | (p2 ? 4u : 0u) | (p3 ? 8u : 0u);
    if (nib) atomicOr(&M[wv][(j0 >> 5) + (lane >> 3)], nib << ((lane & 7) * 4));
    cnt += __popcll(b0) + __popcll(b1) + __popcll(b2) + __popcll(b3);
  }
  if (lane == 0) adj_cnt[row] = (cnt < ADJ_CAP) ? cnt : ADJ_CAP;
  amask[(size_t)row * 64 + lane] = M[wv][lane];
}

// ------- a2 = OR of neighbors' bitmasks, minus diagonal; bit-compact (sorted) -------
__global__ __launch_bounds__(64) void k_a2(
    const int* __restrict__ adj_idx, const int* __restrict__ adj_cnt,
    const unsigned* __restrict__ amask, int* __restrict__ a2_idx,
    int* __restrict__ a2_cnt) {
  int row = blockIdx.x;
  int lane = threadIdx.x;
  int base = (row >> 11) * N_;
  int cnt = adj_cnt[row];
  const int* idx = adj_idx + (size_t)row * ADJ_CAP;
  unsigned m = 0;
  for (int t = 0; t < cnt; t++) {
    int j = idx[t];
    m |= amask[(size_t)(base + j) * 64 + lane];
  }
  int i = row & (N_ - 1);
  if ((i >> 5) == lane) m &= ~(1u << (i & 31));
  int pc = __popc(m);
  int pre = pc;
  #pragma unroll
  for (int o = 1; o < 64; o <<= 1) {
    int t2 = __shfl_up(pre, o);
    if (lane >= o) pre += t2;
  }
  int total = __shfl(pre, 63);
  int k = pre - pc;
  int* out = a2_idx + (size_t)row * A2_CAP;
  int colbase = lane * 32;
  while (m) {
    int bit = __ffs(m) - 1;
    if (k < A2_CAP) out[k] = colbase + bit;
    k++;
    m &= m - 1;
  }
  if (lane == 63) a2_cnt[row] = (total < A2_CAP) ? total : A2_CAP;
}

// ---------------- encoder: direct global weight loads, LDS act broadcast -------------
__global__ __launch_bounds__(256) void k_enc(
    const float* __restrict__ emb, const float* __restrict__ feat,
    const float* __restrict__ W0, const float* __restrict__ b0,
    const float* __restrict__ W1, const float* __restrict__ b1,
    float* __restrict__ h) {
  int tid = threadIdx.x, w = tid >> 6, j = tid & 63;
  int row0 = blockIdx.x * DR;
  __shared__ float XL[DR][FIN_];
  __shared__ float HID[DR][64];
  for (int t = tid; t < DR * FIN_; t += 256) {
    int r = t / FIN_, d = t - r * FIN_;
    int row = row0 + r;
    XL[r][d] = (d < 16) ? emb[(size_t)row * 16 + d] : feat[(size_t)row * 2 + (d - 16)];
  }
  __syncthreads();
  float acc[4];
  float b0j = b0[j];
  #pragma unroll
  for (int r = 0; r < 4; r++) acc[r] = b0j;
  #pragma unroll 2
  for (int d = 0; d < FIN_; d++) {
    float wv = W0[d * 64 + j];
    #pragma unroll
    for (int r = 0; r < 4; r++) acc[r] += XL[w * 4 + r][d] * wv;
  }
  #pragma unroll
  for (int r = 0; r < 4; r++) HID[w * 4 + r][j] = tanhf(acc[r]);
  float b1j = b1[j];
  #pragma unroll
  for (int r = 0; r < 4; r++) acc[r] = b1j;
  for (int dq = 0; dq < 16; dq++) {
    float w0 = W1[(4 * dq + 0) * 64 + j];
    float w1 = W1[(4 * dq + 1) * 64 + j];
    float w2 = W1[(4 * dq + 2) * 64 + j];
    float w3 = W1[(4 * dq + 3) * 64 + j];
    #pragma unroll
    for (int r = 0; r < 4; r++) {
      float4 x = ((const float4*)HID[w * 4 + r])[dq];
      acc[r] += x.x * w0 + x.y * w1 + x.z * w2 + x.w * w3;
    }
  }
  #pragma unroll
  for (int r = 0; r < 4; r++)
    h[(size_t)(row0 + w * 4 + r) * 64 + j] = tanhf(acc[r]);
}

// ---------------- z + attention logits: per-wave head, direct weight loads ----------
__global__ __launch_bounds__(256) void k_z(
    const float* __restrict__ h, const float* __restrict__ attn_W,
    const float* __restrict__ a_src, const float* __restrict__ a_dst,
    float* __restrict__ z, float* __restrict__ ssrc2, float* __restrict__ sdst2) {
  int tid = threadIdx.x, w = tid >> 6, j = tid & 63;
  int head = w & 1, rbase = (w >> 1) * 8;
  int row0 = blockIdx.x * DR;
  __shared__ float HL[DR][64];
  for (int t = tid; t < DR * 64; t += 256) HL[t >> 6][t & 63] = h[(size_t)row0 * 64 + t];
  __syncthreads();
  const float* W = attn_W + head * 64 * 64;
  float acc[8];
  #pragma unroll
  for (int r = 0; r < 8; r++) acc[r] = 0.f;
  for (int dq = 0; dq < 16; dq++) {
    float w0 = W[(4 * dq + 0) * 64 + j];
    float w1 = W[(4 * dq + 1) * 64 + j];
    float w2 = W[(4 * dq + 2) * 64 + j];
    float w3 = W[(4 * dq + 3) * 64 + j];
    #pragma unroll
    for (int r = 0; r < 8; r++) {
      float4 x = ((const float4*)HL[rbase + r])[dq];
      acc[r] += x.x * w0 + x.y * w1 + x.z * w2 + x.w * w3;
    }
  }
  float as = a_src[head * 64 + j], ad = a_dst[head * 64 + j];
  #pragma unroll
  for (int r = 0; r < 8; r++) {
    int row = row0 + rbase + r;
    z[((size_t)head * (B_ * N_) + row) * 64 + j] = acc[r];
    float rs = wave_sum(acc[r] * as), rd = wave_sum(acc[r] * ad);
    if (j == 0) {
      ssrc2[(size_t)row * 2 + head] = rs;
      sdst2[(size_t)row * 2 + head] = rd;
    }
  }
}

// ---------------- adj aggregation: one wave per row, no LDS, no barriers ------------
__global__ __launch_bounds__(64) void k_agg_adj(
    const int* __restrict__ adj_idx, const int* __restrict__ adj_cnt,
    const float* __restrict__ z, const float* __restrict__ ssrc2,
    const float* __restrict__ sdst2, float* __restrict__ aggs) {
  int row = blockIdx.x;
  int lane = threadIdx.x;
  int b = row >> 11;
  int cnt = adj_cnt[row];
  const int* idx = adj_idx + (size_t)row * ADJ_CAP;
  float2 ss = ((const float2*)ssrc2)[row];
  const float2* sd = (const float2*)sdst2 + (size_t)b * N_;
  int col0 = 0, col1 = 0;
  float e00 = 0.f, e10 = 0.f, e01 = 0.f, e11 = 0.f;
  if (lane < cnt) {
    col0 = idx[lane]; float2 s = sd[col0];
    e00 = __expf(tanhf(ss.x + s.x)); e10 = __expf(tanhf(ss.y + s.y));
  }
  if (lane + 64 < cnt) {
    col1 = idx[lane + 64]; float2 s = sd[col1];
    e01 = __expf(tanhf(ss.x + s.x)); e11 = __expf(tanhf(ss.y + s.y));
  }
  float tot0 = wave_sum(e00 + e01), tot1 = wave_sum(e10 + e11);
  float inv0 = (tot0 > 0.f) ? 1.f / tot0 : 0.f;
  float inv1 = (tot1 > 0.f) ? 1.f / tot1 : 0.f;
  const float* z0 = z + (size_t)b * N_ * 64;
  const float* z1 = z + ((size_t)(B_ * N_) + b * N_) * 64;
  int g = lane >> 4, li = lane & 15;
  float4 a0 = {0.f, 0.f, 0.f, 0.f}, a1 = {0.f, 0.f, 0.f, 0.f};
  for (int j0 = 0; j0 < 64; j0 += 4) {
    if (j0 >= cnt) break;
    int j = j0 + g;
    int c = __shfl(col0, j);
    float e0 = __shfl(e00, j), e1 = __shfl(e10, j);
    if (j < cnt) {
      float4 v0 = ((const float4*)(z0 + (size_t)c * 64))[li];
      float4 v1 = ((const float4*)(z1 + (size_t)c * 64))[li];
      a0.x += e0 * v0.x; a0.y += e0 * v0.y; a0.z += e0 * v0.z; a0.w += e0 * v0.w;
      a1.x += e1 * v1.x; a1.y += e1 * v1.y; a1.z += e1 * v1.z; a1.w += e1 * v1.w;
    }
  }
  if (cnt > 64) {
    for (int j0 = 0; j0 < 64; j0 += 4) {
      if (64 + j0 >= cnt) break;
      int j = j0 + g;
      int c = __shfl(col1, j);
      float e0 = __shfl(e01, j), e1 = __shfl(e11, j);
      if (64 + j < cnt) {
        float4 v0 = ((const float4*)(z0 + (size_t)c * 64))[li];
        float4 v1 = ((const float4*)(z1 + (size_t)c * 64))[li];
        a0.x += e0 * v0.x; a0.y += e0 * v0.y; a0.z += e0 * v0.z; a0.w += e0 * v0.w;
        a1.x += e1 * v1.x; a1.y += e1 * v1.y; a1.z += e1 * v1.z; a1.w += e1 * v1.w;
      }
    }
  }
  grp_reduce(a0); grp_reduce(a1);
  if (g == 0) {
    float4 o;
    o.x = tanhf(0.5f * (a0.x * inv0 + a1.x * inv1));
    o.y = tanhf(0.5f * (a0.y * inv0 + a1.y * inv1));
    o.z = tanhf(0.5f * (a0.z * inv0 + a1.z * inv1));
    o.w = tanhf(0.5f * (a0.w * inv0 + a1.w * inv1));
    ((float4*)(aggs + ((size_t)row * 2 + 0) * 64))[li] = o;
  }
}

// ---------------- a2 aggregation: 256 thr, registers + shfl, single barrier ---------
__global__ __launch_bounds__(256) void k_agg_a2(
    const int* __restrict__ a2_idx, const int* __restrict__ a2_cnt,
    const float* __restrict__ z, const float* __restrict__ ssrc2,
    const float* __restrict__ sdst2, float* __restrict__ aggs) {
  int row = blockIdx.x;
  int tid = threadIdx.x;
  int w = tid >> 6, lane = tid & 63;
  int b = row >> 11;
  int cnt = a2_cnt[row];
  const int* idx = a2_idx + (size_t)row * A2_CAP;
  float2 ss = ((const float2*)ssrc2)[row];
  const float2* sd = (const float2*)sdst2 + (size_t)b * N_;
  int colr[4]; float e0r[4], e1r[4];
  float s0 = 0.f, s1 = 0.f;
  #pragma unroll
  for (int c = 0; c < 4; c++) {
    int t = c * 256 + tid;
    colr[c] = 0; e0r[c] = 0.f; e1r[c] = 0.f;
    if (t < cnt) {
      int cc = idx[t]; colr[c] = cc;
      float2 s = sd[cc];
      e0r[c] = __expf(tanhf(ss.x + s.x));
      e1r[c] = __expf(tanhf(ss.y + s.y));
      s0 += e0r[c]; s1 += e1r[c];
    }
  }
  s0 = wave_sum(s0); s1 = wave_sum(s1);
  __shared__ float RED[2][4];
  __shared__ float WS0[4][64], WS1[4][64];
  if (lane == 0) { RED[0][w] = s0; RED[1][w] = s1; }
  const float* z0 = z + (size_t)b * N_ * 64;
  const float* z1 = z + ((size_t)(B_ * N_) + b * N_) * 64;
  int g = lane >> 4, li = lane & 15;
  float4 a0 = {0.f, 0.f, 0.f, 0.f}, a1 = {0.f, 0.f, 0.f, 0.f};
  #pragma unroll
  for (int c = 0; c < 4; c++) {
    int base = c * 256 + w * 64;
    if (base >= cnt) break;
    for (int j0 = 0; j0 < 64; j0 += 4) {
      if (base + j0 >= cnt) break;
      int j = j0 + g;
      int col = __shfl(colr[c], j);
      float e0 = __shfl(e0r[c], j), e1 = __shfl(e1r[c], j);
      if (base + j < cnt) {
        float4 v0 = ((const float4*)(z0 + (size_t)col * 64))[li];
        float4 v1 = ((const float4*)(z1 + (size_t)col * 64))[li];
        a0.x += e0 * v0.x; a0.y += e0 * v0.y; a0.z += e0 * v0.z; a0.w += e0 * v0.w;
        a1.x += e1 * v1.x; a1.y += e1 * v1.y; a1.z += e1 * v1.z; a1.w += e1 * v1.w;
      }
    }
  }
  grp_reduce(a0); grp_reduce(a1);
  if (g == 0) {
    ((float4*)WS0[w])[li] = a0;
    ((float4*)WS1[w])[li] = a1;
  }
  __syncthreads();
  if (tid < 64) {
    float tot0 = RED[0][0] + RED[0][1] + RED[0][2] + RED[0][3];
    float tot1 = RED[1][0] + RED[1][1] + RED[1][2] + RED[1][3];
    float inv0 = (tot0 > 0.f) ? 1.f / tot0 : 0.f;
    float inv1 = (tot1 > 0.f) ? 1.f / tot1 : 0.f;
    float r0 = WS0[0][tid] + WS0[1][tid] + WS0[2][tid] + WS0[3][tid];
    float r1 = WS1[0][tid] + WS1[1][tid] + WS1[2][tid] + WS1[3][tid];
    aggs[((size_t)row * 2 + 1) * 64 + tid] = tanhf(0.5f * (r0 * inv0 + r1 * inv1));
  }
}

// ---------------- nbr-softmax combine + GRU: direct weight loads, no arrays ---------
__global__ __launch_bounds__(256) void k_comb(
    const float* __restrict__ aggs, const float* __restrict__ nbr_q,
    const float* __restrict__ gru_W, const float* __restrict__ gru_U,
    const float* __restrict__ gru_b, float* __restrict__ h) {
  int tid = threadIdx.x, w = tid >> 6, j = tid & 63;
  int row0 = blockIdx.x * DR;
  __shared__ float HL[DR][64], NL[DR][64], RGL[DR][64];
  for (int t = tid; t < DR * 64; t += 256) HL[t >> 6][t & 63] = h[(size_t)row0 * 64 + t];
  float q = nbr_q[j];
  #pragma unroll
  for (int r = 0; r < 4; r++) {
    int rr = w * 4 + r, row = row0 + rr;
    float a0 = aggs[((size_t)row * 2 + 0) * 64 + j];
    float a1 = aggs[((size_t)row * 2 + 1) * 64 + j];
    float t0 = tanhf(wave_sum(a0 * q));
    float t1 = tanhf(wave_sum(a1 * q));
    float mx = fmaxf(t0, t1);
    float e0 = __expf(t0 - mx), e1 = __expf(t1 - mx);
    float inv = 1.f / (e0 + e1);
    NL[rr][j] = (e0 * a0 + e1 * a1) * inv;
  }
  __syncthreads();  // HL staging; NL/RGL rows are same-wave
  float az[4], ar[4];
  float bz = gru_b[j], br = gru_b[64 + j];
  #pragma unroll
  for (int r = 0; r < 4; r++) { az[r] = bz; ar[r] = br; }
  for (int dq = 0; dq < 16; dq++) {
    int d0 = 4 * dq;
    float wz0 = gru_W[(d0 + 0) * 192 + j],      wz1 = gru_W[(d0 + 1) * 192 + j];
    float wz2 = gru_W[(d0 + 2) * 192 + j],      wz3 = gru_W[(d0 + 3) * 192 + j];
    float wr0 = gru_W[(d0 + 0) * 192 + 64 + j], wr1 = gru_W[(d0 + 1) * 192 + 64 + j];
    float wr2 = gru_W[(d0 + 2) * 192 + 64 + j], wr3 = gru_W[(d0 + 3) * 192 + 64 + j];
    float uz0 = gru_U[(d0 + 0) * 192 + j],      uz1 = gru_U[(d0 + 1) * 192 + j];
    float uz2 = gru_U[(d0 + 2) * 192 + j],      uz3 = gru_U[(d0 + 3) * 192 + j];
    float ur0 = gru_U[(d0 + 0) * 192 + 64 + j], ur1 = gru_U[(d0 + 1) * 192 + 64 + j];
    float ur2 = gru_U[(d0 + 2) * 192 + 64 + j], ur3 = gru_U[(d0 + 3) * 192 + 64 + j];
    #pragma unroll
    for (int r = 0; r < 4; r++) {
      float4 n = ((const float4*)NL[w * 4 + r])[dq];
      float4 x = ((const float4*)HL[w * 4 + r])[dq];
      az[r] += n.x * wz0 + n.y * wz1 + n.z * wz2 + n.w * wz3
             + x.x * uz0 + x.y * uz1 + x.z * uz2 + x.w * uz3;
      ar[r] += n.x * wr0 + n.y * wr1 + n.z * wr2 + n.w * wr3
             + x.x * ur0 + x.y * ur1 + x.z * ur2 + x.w * ur3;
    }
  }
  float zgr[4];
  #pragma unroll
  for (int r = 0; r < 4; r++) {
    zgr[r] = 1.f / (1.f + __expf(-az[r]));
    RGL[w * 4 + r][j] = 1.f / (1.f + __expf(-ar[r]));  // same-wave rows
  }
  float ah[4];
  float bh = gru_b[128 + j];
  #pragma unroll
  for (int r = 0; r < 4; r++) ah[r] = bh;
  for (int dq = 0; dq < 16; dq++) {
    int d0 = 4 * dq;
    float wh0 = gru_W[(d0 + 0) * 192 + 128 + j], wh1 = gru_W[(d0 + 1) * 192 + 128 + j];
    float wh2 = gru_W[(d0 + 2) * 192 + 128 + j], wh3 = gru_W[(d0 + 3) * 192 + 128 + j];
    float uh0 = gru_U[(d0 + 0) * 192 + 128 + j], uh1 = gru_U[(d0 + 1) * 192 + 128 + j];
    float uh2 = gru_U[(d0 + 2) * 192 + 128 + j], uh3 = gru_U[(d0 + 3) * 192 + 128 + j];
    #pragma unroll
    for (int r = 0; r < 4; r++) {
      float4 n = ((const float4*)NL[w * 4 + r])[dq];
      float4 x = ((const float4*)HL[w * 4 + r])[dq];
      float4 rg = ((const float4*)RGL[w * 4 + r])[dq];
      ah[r] += n.x * wh0 + n.y * wh1 + n.z * wh2 + n.w * wh3
             + rg.x * x.x * uh0 + rg.y * x.y * uh1
             + rg.z * x.z * uh2 + rg.w * x.w * uh3;
    }
  }
  #pragma unroll
  for (int r = 0; r < 4; r++) {
    int rr = w * 4 + r;
    float ht = tanhf(ah[r]);
    float hj = HL[rr][j];
    h[(size_t)(row0 + rr) * 64 + j] = (1.f - zgr[r]) * hj + zgr[r] * ht;
  }
}

// ---------------- decoder + dual heads: direct weight loads ----------------
__global__ __launch_bounds__(256) void k_dec(
    const float* __restrict__ h, const float* __restrict__ dW0,
    const float* __restrict__ db0, const float* __restrict__ dW1,
    const float* __restrict__ db1, const float* __restrict__ uW0,
    const float* __restrict__ ub0, const float* __restrict__ uW1,
    const float* __restrict__ ub1, const float* __restrict__ demands,
    float* __restrict__ nw, float* __restrict__ dv, float* accum) {
  int tid = threadIdx.x, w = tid >> 6, j = tid & 63;
  int row0 = blockIdx.x * DR;
  __shared__ float HL[DR][64];
  __shared__ float DD[4];
  for (int t = tid; t < DR * 64; t += 256) HL[t >> 6][t & 63] = h[(size_t)row0 * 64 + t];
  __syncthreads();
  float accd[4], accu[4];
  float db0j = db0[j], ub0j = ub0[j];
  #pragma unroll
  for (int r = 0; r < 4; r++) { accd[r] = db0j; accu[r] = ub0j; }
  for (int dq = 0; dq < 16; dq++) {
    int d0 = 4 * dq;
    float dw0 = dW0[(d0 + 0) * 64 + j], dw1 = dW0[(d0 + 1) * 64 + j];
    float dw2 = dW0[(d0 + 2) * 64 + j], dw3 = dW0[(d0 + 3) * 64 + j];
    float uw0 = uW0[(d0 + 0) * 64 + j], uw1 = uW0[(d0 + 1) * 64 + j];
    float uw2 = uW0[(d0 + 2) * 64 + j], uw3 = uW0[(d0 + 3) * 64 + j];
    #pragma unroll
    for (int r = 0; r < 4; r++) {
      float4 x = ((const float4*)HL[w * 4 + r])[dq];
      accd[r] += x.x * dw0 + x.y * dw1 + x.z * dw2 + x.w * dw3;
      accu[r] += x.x * uw0 + x.y * uw1 + x.z * uw2 + x.w * uw3;
    }
  }
  float dw1c = dW1[j], uw1c = uW1[j];
  float db1s = db1[0], ub1s = ub1[0];
  float ddl = 0.f;
  #pragma unroll
  for (int r = 0; r < 4; r++) {
    int row = row0 + w * 4 + r;
    float a = wave_sum(tanhf(accd[r]) * dw1c);
    float bb = wave_sum(tanhf(accu[r]) * uw1c);
    if (j == 0) {
      float dvv = bb + ub1s;
      nw[row] = a + db1s; dv[row] = dvv;
      ddl += dvv * demands[row];
    }
  }
  if (j == 0) DD[w] = ddl;
  __syncthreads();
  if (tid == 0) atomicAdd(&accum[4 + (row0 >> 11)], DD[0] + DD[1] + DD[2] + DD[3]);
}

// ------- cooperative tail: propT + 9 MCF iterations + flowdual + finalize -----------
// grid = 128 blocks x 256 threads (co-resident), 11 grid syncs.
__global__ __launch_bounds__(256) void k_tail(
    const int* __restrict__ adj_idx, const int* __restrict__ adj_cnt,
    const float* __restrict__ nw, const float* __restrict__ demands,
    float* __restrict__ Pval, int* __restrict__ tcnt,
    int* __restrict__ tsrc, float* __restrict__ tval,
    float* __restrict__ sA, float* __restrict__ sB,
    const float* __restrict__ dv, float* accum, float* out) {
  cg::grid_group grid = cg::this_grid();
  int tid = threadIdx.x;
  int wv = tid >> 6, lane = tid & 63;
  int gwave = blockIdx.x * 4 + wv;          // 0..511
  int gtid = blockIdx.x * 256 + tid;        // 0..32767
  // ---- phase 1: row softmax P + transpose scatter + s_1 init (8 rows per wave) ----
  for (int row = gwave; row < B_ * N_; row += 512) {
    int b = row >> 11;
    int base = b * N_;
    int cnt = adj_cnt[row];
    const int* idx = adj_idx + (size_t)row * ADJ_CAP;
    int c0 = (lane < cnt) ? idx[lane] : -1;
    int c1 = (lane + 64 < cnt) ? idx[lane + 64] : -1;
    float v0 = (c0 >= 0) ? nw[base + c0] : -1e30f;
    float v1 = (c1 >= 0) ? nw[base + c1] : -1e30f;
    float m = wave_max(fmaxf(v0, v1));
    float e0 = (c0 >= 0) ? __expf(v0 - m) : 0.f;
    float e1 = (c1 >= 0) ? __expf(v1 - m) : 0.f;
    float s = wave_sum(e0 + e1);
    float inv = (s > 0.f) ? 1.f / s : 0.f;
    float p0 = e0 * inv, p1 = e1 * inv;
    if (c0 >= 0) {
      Pval[(size_t)row * ADJ_CAP + lane] = p0;
      int col = base + c0;
      int pos = atomicAdd(&tcnt[col], 1);
      if (pos < ADJ_CAP) {
        tsrc[(size_t)col * ADJ_CAP + pos] = row;
        tval[(size_t)col * ADJ_CAP + pos] = p0;
      }
    }
    if (c1 >= 0) {
      Pval[(size_t)row * ADJ_CAP + lane + 64] = p1;
      int col = base + c1;
      int pos = atomicAdd(&tcnt[col], 1);
      if (pos < ADJ_CAP) {
        tsrc[(size_t)col * ADJ_CAP + pos] = row;
        tval[(size_t)col * ADJ_CAP + pos] = p1;
      }
    }
    if (lane == 0) sA[row] = fmaxf(-demands[row], 0.f);
  }
  __threadfence();
  grid.sync();
  // ---- phase 2: 9 MCF iterations (ping-pong sA/sB), one thread per column ----
  int myc = -1, mycnt = 0;
  const int* msrc = nullptr; const float* mval = nullptr;
  float mdem = 0.f;
  if (gtid < B_ * N_) {
    myc = gtid;
    mycnt = tcnt[myc];
    msrc = tsrc + (size_t)myc * ADJ_CAP;
    mval = tval + (size_t)myc * ADJ_CAP;
    mdem = demands[myc];
  }
  for (int it = 0; it < 9; it++) {
    const float* sin = (it & 1) ? sB : sA;
    float* sout = (it & 1) ? sA : sB;
    if (myc >= 0) {
      float c = 0.f;
      int c4 = mycnt >> 2;
      for (int q = 0; q < c4; q++) {
        int4 s4 = ((const int4*)msrc)[q];
        float4 v4 = ((const float4*)mval)[q];
        c += v4.x * sin[s4.x] + v4.y * sin[s4.y] + v4.z * sin[s4.z] + v4.w * sin[s4.w];
      }
      for (int t = c4 * 4; t < mycnt; t++) c += mval[t] * sin[msrc[t]];
      sout[myc] = fmaxf(c - mdem, 0.f);
    }
    __threadfence();
    grid.sync();
  }
  // ---- phase 3: flow cost + dual recurrence; 16-lane group per row, 2 rows each ----
  const float* sfin = sB;  // it=8 wrote sB
  int grp = gwave * 4 + (lane >> 4);  // 0..2047
  int e = lane & 15;
  float fcb[2] = {0.f, 0.f}, dcb[2] = {0.f, 0.f};
  for (int pass = 0; pass < 2; pass++) {
    int row = grp + pass * 2048;
    int b = row >> 11, i = row & (N_ - 1);
    int cnt = adj_cnt[row];
    float si = sfin[row], dvi = dv[row];
    const int* idx = adj_idx + (size_t)row * ADJ_CAP;
    const float* pv = Pval + (size_t)row * ADJ_CAP;
    float fc = 0.f, dc = 0.f;
    for (int t = e; t < cnt; t += 16) {
      int j = idx[t];
      float f_ij = si * pv[t];
      const int* jidx = adj_idx + (size_t)(b * N_ + j) * ADJ_CAP;
      int jcnt = adj_cnt[b * N_ + j];
      int lo = 0, hi = jcnt, pos = -1;
      while (lo < hi) {
        int mid = (lo + hi) >> 1;
        int v = jidx[mid];
        if (v == i) { pos = mid; break; }
        if (v < i) lo = mid + 1; else hi = mid;
      }
      float f_ji = (pos >= 0) ? sfin[b * N_ + j] * Pval[(size_t)(b * N_ + j) * ADJ_CAP + pos] : 0.f;
      float fin = f_ij - fminf(f_ij, f_ji);
      fc += fin * fin;
      float dd = dvi - dv[b * N_ + j];
      float y = 0.f, m = 0.f;
      #pragma unroll
      for (int q = 0; q < 10; q++) {
        float g2 = 2.f * y - dd;
        m = 0.9f * m + g2;
        y = fmaxf(y - 0.1f * m, 0.f);
      }
      dc += y * y - dd * y;
    }
    fcb[b] += fc; dcb[b] += dc;
  }
  // 16-lane group reduce
  #pragma unroll
  for (int o = 1; o < 16; o <<= 1) {
    fcb[0] += __shfl_xor(fcb[0], o); fcb[1] += __shfl_xor(fcb[1], o);
    dcb[0] += __shfl_xor(dcb[0], o); dcb[1] += __shfl_xor(dcb[1], o);
  }
  __shared__ float R[4][16];
  int gidx = wv * 4 + (lane >> 4);
  if (e == 0) {
    R[0][gidx] = fcb[0]; R[1][gidx] = fcb[1];
    R[2][gidx] = dcb[0]; R[3][gidx] = dcb[1];
  }
  __syncthreads();
  if (tid < 4) {
    float s = 0.f;
    #pragma unroll
    for (int q = 0; q < 16; q++) s += R[tid][q];
    // tid0 -> accum[0] (fc b0), tid1 -> accum[1] (fc b1),
    // tid2 -> accum[2] (dc b0), tid3 -> accum[3] (dc b1)
    atomicAdd(&accum[(tid & 1) + ((tid >> 1) << 1)], s);  // = accum[tid]
  }
  __threadfence();
  grid.sync();
  // ---- phase 4: finalize ----
  if (blockIdx.x == 0 && tid < B_)
    out[tid] = accum[tid] - accum[2 + tid] + accum[4 + tid];
}

extern "C" void kernel_launch(void* const* d_in, const int* in_sizes, int n_in,
                              void* d_out, int out_size, void* d_ws, size_t ws_size,
                              hipStream_t stream) {
  const float* feat    = (const float*)d_in[0];
  const float* emb     = (const float*)d_in[1];
  const float* demands = (const float*)d_in[2];
  // d_in[3] (adj) == neighborhoods[0]; not read.
  const float* nbhd    = (const float*)d_in[4];
  const float* enc_W0  = (const float*)d_in[5];
  const float* enc_b0  = (const float*)d_in[6];
  const float* enc_W1  = (const float*)d_in[7];
  const float* enc_b1  = (const float*)d_in[8];
  const float* attn_W  = (const float*)d_in[9];
  const float* a_src   = (const float*)d_in[10];
  const float* a_dst   = (const float*)d_in[11];
  const float* nbr_q   = (const float*)d_in[12];
  const float* gru_W   = (const float*)d_in[13];
  const float* gru_U   = (const float*)d_in[14];
  const float* gru_b   = (const float*)d_in[15];
  const float* dec_W0  = (const float*)d_in[16];
  const float* dec_b0  = (const float*)d_in[17];
  const float* dec_W1  = (const float*)d_in[18];
  const float* dec_b1  = (const float*)d_in[19];
  const float* dual_W0 = (const float*)d_in[20];
  const float* dual_b0 = (const float*)d_in[21];
  const float* dual_W1 = (const float*)d_in[22];
  const float* dual_b1 = (const float*)d_in[23];
  float* out = (float*)d_out;

  char* ws = (char*)d_ws;
  size_t off = 0;
  auto alloc = [&](size_t bytes) { char* p = ws + off; off += (bytes + 255) & ~(size_t)255; return p; };
  int*      adj_idx = (int*)     alloc((size_t)B_ * N_ * ADJ_CAP * 4);
  int*      adj_cnt = (int*)     alloc((size_t)B_ * N_ * 4);
  unsigned* amask   = (unsigned*)alloc((size_t)B_ * N_ * 64 * 4);
  int*      a2_idx  = (int*)     alloc((size_t)B_ * N_ * A2_CAP * 4);
  int*      a2_cnt  = (int*)     alloc((size_t)B_ * N_ * 4);
  float*    h       = (float*)   alloc((size_t)B_ * N_ * 64 * 4);
  float*    z       = (float*)   alloc((size_t)2 * B_ * N_ * 64 * 4);
  float*    ssrc2   = (float*)   alloc((size_t)2 * B_ * N_ * 4);
  float*    sdst2   = (float*)   alloc((size_t)2 * B_ * N_ * 4);
  float*    aggs    = (float*)   alloc((size_t)B_ * N_ * 2 * 64 * 4);
  float*    nw      = (float*)   alloc((size_t)B_ * N_ * 4);
  float*    dv      = (float*)   alloc((size_t)B_ * N_ * 4);
  float*    Pval    = (float*)   alloc((size_t)B_ * N_ * ADJ_CAP * 4);
  int*      tcnt    = (int*)     alloc((size_t)B_ * N_ * 4);
  int*      tsrc    = (int*)     alloc((size_t)B_ * N_ * ADJ_CAP * 4);
  float*    tval    = (float*)   alloc((size_t)B_ * N_ * ADJ_CAP * 4);
  float*    sA      = (float*)   alloc((size_t)B_ * N_ * 4);
  float*    sB      = (float*)   alloc((size_t)B_ * N_ * 4);
  float*    accum   = (float*)   alloc(8 * 4);

  k_csr_adj<<<(B_ * N_) / 4, 256, 0, stream>>>(nbhd, adj_idx, adj_cnt, amask, accum, tcnt);
  k_a2<<<B_ * N_, 64, 0, stream>>>(adj_idx, adj_cnt, amask, a2_idx, a2_cnt);
  k_enc<<<(B_ * N_) / DR, 256, 0, stream>>>(emb, feat, enc_W0, enc_b0, enc_W1, enc_b1, h);
  for (int layer = 0; layer < 2; layer++) {
    k_z<<<(B_ * N_) / DR, 256, 0, stream>>>(h, attn_W, a_src, a_dst, z, ssrc2, sdst2);
    k_agg_adj<<<B_ * N_, 64, 0, stream>>>(adj_idx, adj_cnt, z, ssrc2, sdst2, aggs);
    k_agg_a2<<<B_ * N_, 256, 0, stream>>>(a2_idx, a2_cnt, z, ssrc2, sdst2, aggs);
    k_comb<<<(B_ * N_) / DR, 256, 0, stream>>>(aggs, nbr_q, gru_W, gru_U, gru_b, h);
  }
  k_dec<<<(B_ * N_) / DR, 256, 0, stream>>>(h, dec_W0, dec_b0, dec_W1, dec_b1,
                                            dual_W0, dual_b0, dual_W1, dual_b1,
                                            demands, nw, dv, accum);
  {
    void* args[] = {
      (void*)&adj_idx, (void*)&adj_cnt, (void*)&nw, (void*)&demands,
      (void*)&Pval, (void*)&tcnt, (void*)&tsrc, (void*)&tval,
      (void*)&sA, (void*)&sB, (void*)&dv, (void*)&accum, (void*)&out
    };
    hipLaunchCooperativeKernel((const void*)k_tail, dim3(128), dim3(256), args, 0, stream);
  }
}

// Round 11
// 378.765 us; speedup vs baseline: 1.8480x; 1.8480x over previous
//
#include <hip/hip_runtime.h>

#define B_ 2
#define N_ 2048
#define E_ 64
#define FIN_ 18
#define ADJ_CAP 128
#define A2_CAP 1024
#define DR 16  // rows per block in dense kernels

__device__ __forceinline__ float wave_sum(float v) {
  #pragma unroll
  for (int o = 32; o > 0; o >>= 1) v += __shfl_xor(v, o);
  return v;
}
__device__ __forceinline__ float wave_max(float v) {
  #pragma unroll
  for (int o = 32; o > 0; o >>= 1) v = fmaxf(v, __shfl_xor(v, o));
  return v;
}
__device__ __forceinline__ void grp_reduce(float4& a) {
  #pragma unroll
  for (int o = 16; o <= 32; o <<= 1) {
    a.x += __shfl_xor(a.x, o); a.y += __shfl_xor(a.y, o);
    a.z += __shfl_xor(a.z, o); a.w += __shfl_xor(a.w, o);
  }
}

// ------- adj-only CSR scan + per-row 2048-bit adjacency bitmask; zero accum/tcnt ----
__global__ void k_csr_adj(const float* __restrict__ nbhd, int* __restrict__ adj_idx,
                          int* __restrict__ adj_cnt, unsigned* __restrict__ amask,
                          float* __restrict__ accum, int* __restrict__ tcnt) {
  int wv = threadIdx.x >> 6;
  int row = blockIdx.x * 4 + wv;  // 0..B*N-1
  int lane = threadIdx.x & 63;
  if (row == 0 && lane < 8) accum[lane] = 0.f;
  if (lane == 0) tcnt[row] = 0;
  __shared__ unsigned M[4][64];
  M[wv][lane] = 0;  // same-wave use only
  const float* r = nbhd + (size_t)row * N_;
  int* idx = adj_idx + (size_t)row * ADJ_CAP;
  int cnt = 0;
  unsigned long long below = (1ull << lane) - 1ull;
  for (int j0 = 0; j0 < N_; j0 += 256) {
    float4 v = ((const float4*)(r + j0))[lane];
    bool p0 = v.x > 0.f, p1 = v.y > 0.f, p2 = v.z > 0.f, p3 = v.w > 0.f;
    unsigned long long b0 = __ballot(p0), b1 = __ballot(p1),
                       b2 = __ballot(p2), b3 = __ballot(p3);
    int pos = cnt + __popcll(b0 & below) + __popcll(b1 & below) +
              __popcll(b2 & below) + __popcll(b3 & below);
    int base_j = j0 + lane * 4;
    if (p0) { if (pos < ADJ_CAP) idx[pos] = base_j;     pos++; }
    if (p1) { if (pos < ADJ_CAP) idx[pos] = base_j + 1; pos++; }
    if (p2) { if (pos < ADJ_CAP) idx[pos] = base_j + 2; pos++; }
    if (p3) { if (pos < ADJ_CAP) idx[pos] = base_j + 3; pos++; }
    unsigned nib = (p0 ? 1u : 0u) | (p1 ? 2u : 0u) | (p2 ? 4u : 0u) | (p3 ? 8u : 0u);
    if (nib) atomicOr(&M[wv][(j0 >> 5) + (lane >> 3)], nib << ((lane & 7) * 4));
    cnt += __popcll(b0) + __popcll(b1) + __popcll(b2) + __popcll(b3);
  }
  if (lane == 0) adj_cnt[row] = (cnt < ADJ_CAP) ? cnt : ADJ_CAP;
  amask[(size_t)row * 64 + lane] = M[wv][lane];
}

// ------- a2 = OR of neighbors' bitmasks, minus diagonal; bit-compact (sorted) -------
__global__ __launch_bounds__(64) void k_a2(
    const int* __restrict__ adj_idx, const int* __restrict__ adj_cnt,
    const unsigned* __restrict__ amask, int* __restrict__ a2_idx,
    int* __restrict__ a2_cnt) {
  int row = blockIdx.x;
  int lane = threadIdx.x;
  int base = (row >> 11) * N_;
  int cnt = adj_cnt[row];
  const int* idx = adj_idx + (size_t)row * ADJ_CAP;
  unsigned m = 0;
  for (int t = 0; t < cnt; t++) {
    int j = idx[t];
    m |= amask[(size_t)(base + j) * 64 + lane];
  }
  int i = row & (N_ - 1);
  if ((i >> 5) == lane) m &= ~(1u << (i & 31));
  int pc = __popc(m);
  int pre = pc;
  #pragma unroll
  for (int o = 1; o < 64; o <<= 1) {
    int t2 = __shfl_up(pre, o);
    if (lane >= o) pre += t2;
  }
  int total = __shfl(pre, 63);
  int k = pre - pc;
  int* out = a2_idx + (size_t)row * A2_CAP;
  int colbase = lane * 32;
  while (m) {
    int bit = __ffs(m) - 1;
    if (k < A2_CAP) out[k] = colbase + bit;
    k++;
    m &= m - 1;
  }
  if (lane == 63) a2_cnt[row] = (total < A2_CAP) ? total : A2_CAP;
}

// ---------------- encoder: direct global weight loads, LDS act broadcast -------------
__global__ __launch_bounds__(256) void k_enc(
    const float* __restrict__ emb, const float* __restrict__ feat,
    const float* __restrict__ W0, const float* __restrict__ b0,
    const float* __restrict__ W1, const float* __restrict__ b1,
    float* __restrict__ h) {
  int tid = threadIdx.x, w = tid >> 6, j = tid & 63;
  int row0 = blockIdx.x * DR;
  __shared__ float XL[DR][FIN_];
  __shared__ float HID[DR][64];
  for (int t = tid; t < DR * FIN_; t += 256) {
    int r = t / FIN_, d = t - r * FIN_;
    int row = row0 + r;
    XL[r][d] = (d < 16) ? emb[(size_t)row * 16 + d] : feat[(size_t)row * 2 + (d - 16)];
  }
  __syncthreads();
  float acc[4];
  float b0j = b0[j];
  #pragma unroll
  for (int r = 0; r < 4; r++) acc[r] = b0j;
  #pragma unroll 2
  for (int d = 0; d < FIN_; d++) {
    float wv = W0[d * 64 + j];
    #pragma unroll
    for (int r = 0; r < 4; r++) acc[r] += XL[w * 4 + r][d] * wv;
  }
  #pragma unroll
  for (int r = 0; r < 4; r++) HID[w * 4 + r][j] = tanhf(acc[r]);
  float b1j = b1[j];
  #pragma unroll
  for (int r = 0; r < 4; r++) acc[r] = b1j;
  for (int dq = 0; dq < 16; dq++) {
    float w0 = W1[(4 * dq + 0) * 64 + j];
    float w1 = W1[(4 * dq + 1) * 64 + j];
    float w2 = W1[(4 * dq + 2) * 64 + j];
    float w3 = W1[(4 * dq + 3) * 64 + j];
    #pragma unroll
    for (int r = 0; r < 4; r++) {
      float4 x = ((const float4*)HID[w * 4 + r])[dq];
      acc[r] += x.x * w0 + x.y * w1 + x.z * w2 + x.w * w3;
    }
  }
  #pragma unroll
  for (int r = 0; r < 4; r++)
    h[(size_t)(row0 + w * 4 + r) * 64 + j] = tanhf(acc[r]);
}

// ---------------- z + attention logits: per-wave head, direct weight loads ----------
__global__ __launch_bounds__(256) void k_z(
    const float* __restrict__ h, const float* __restrict__ attn_W,
    const float* __restrict__ a_src, const float* __restrict__ a_dst,
    float* __restrict__ z, float* __restrict__ ssrc2, float* __restrict__ sdst2) {
  int tid = threadIdx.x, w = tid >> 6, j = tid & 63;
  int head = w & 1, rbase = (w >> 1) * 8;
  int row0 = blockIdx.x * DR;
  __shared__ float HL[DR][64];
  for (int t = tid; t < DR * 64; t += 256) HL[t >> 6][t & 63] = h[(size_t)row0 * 64 + t];
  __syncthreads();
  const float* W = attn_W + head * 64 * 64;
  float acc[8];
  #pragma unroll
  for (int r = 0; r < 8; r++) acc[r] = 0.f;
  for (int dq = 0; dq < 16; dq++) {
    float w0 = W[(4 * dq + 0) * 64 + j];
    float w1 = W[(4 * dq + 1) * 64 + j];
    float w2 = W[(4 * dq + 2) * 64 + j];
    float w3 = W[(4 * dq + 3) * 64 + j];
    #pragma unroll
    for (int r = 0; r < 8; r++) {
      float4 x = ((const float4*)HL[rbase + r])[dq];
      acc[r] += x.x * w0 + x.y * w1 + x.z * w2 + x.w * w3;
    }
  }
  float as = a_src[head * 64 + j], ad = a_dst[head * 64 + j];
  #pragma unroll
  for (int r = 0; r < 8; r++) {
    int row = row0 + rbase + r;
    z[((size_t)head * (B_ * N_) + row) * 64 + j] = acc[r];
    float rs = wave_sum(acc[r] * as), rd = wave_sum(acc[r] * ad);
    if (j == 0) {
      ssrc2[(size_t)row * 2 + head] = rs;
      sdst2[(size_t)row * 2 + head] = rd;
    }
  }
}

// ------- merged aggregation: blocks [0,BN) = a2 (8 waves); [BN,2BN) = adj (wave 0) ---
__global__ __launch_bounds__(512) void k_agg(
    const int* __restrict__ adj_idx, const int* __restrict__ adj_cnt,
    const int* __restrict__ a2_idx, const int* __restrict__ a2_cnt,
    const float* __restrict__ z, const float* __restrict__ ssrc2,
    const float* __restrict__ sdst2, float* __restrict__ aggs) {
  int tid = threadIdx.x, w = tid >> 6, lane = tid & 63;
  if (blockIdx.x >= B_ * N_) {
    // ---------------- adj path: single wave, no LDS, no barriers ----------------
    if (w != 0) return;
    int row = blockIdx.x - B_ * N_;
    int b = row >> 11;
    int cnt = adj_cnt[row];
    const int* idx = adj_idx + (size_t)row * ADJ_CAP;
    float2 ss = ((const float2*)ssrc2)[row];
    const float2* sd = (const float2*)sdst2 + (size_t)b * N_;
    int col0 = 0, col1 = 0;
    float e00 = 0.f, e10 = 0.f, e01 = 0.f, e11 = 0.f;
    if (lane < cnt) {
      col0 = idx[lane]; float2 s = sd[col0];
      e00 = __expf(tanhf(ss.x + s.x)); e10 = __expf(tanhf(ss.y + s.y));
    }
    if (lane + 64 < cnt) {
      col1 = idx[lane + 64]; float2 s = sd[col1];
      e01 = __expf(tanhf(ss.x + s.x)); e11 = __expf(tanhf(ss.y + s.y));
    }
    float tot0 = wave_sum(e00 + e01), tot1 = wave_sum(e10 + e11);
    float inv0 = (tot0 > 0.f) ? 1.f / tot0 : 0.f;
    float inv1 = (tot1 > 0.f) ? 1.f / tot1 : 0.f;
    const float* z0 = z + (size_t)b * N_ * 64;
    const float* z1 = z + ((size_t)(B_ * N_) + b * N_) * 64;
    int g = lane >> 4, li = lane & 15;
    float4 a0 = {0.f, 0.f, 0.f, 0.f}, a1 = {0.f, 0.f, 0.f, 0.f};
    for (int j0 = 0; j0 < 64; j0 += 4) {
      if (j0 >= cnt) break;
      int j = j0 + g;
      int c = __shfl(col0, j);
      float e0 = __shfl(e00, j), e1 = __shfl(e10, j);
      if (j < cnt) {
        float4 v0 = ((const float4*)(z0 + (size_t)c * 64))[li];
        float4 v1 = ((const float4*)(z1 + (size_t)c * 64))[li];
        a0.x += e0 * v0.x; a0.y += e0 * v0.y; a0.z += e0 * v0.z; a0.w += e0 * v0.w;
        a1.x += e1 * v1.x; a1.y += e1 * v1.y; a1.z += e1 * v1.z; a1.w += e1 * v1.w;
      }
    }
    if (cnt > 64) {
      for (int j0 = 0; j0 < 64; j0 += 4) {
        if (64 + j0 >= cnt) break;
        int j = j0 + g;
        int c = __shfl(col1, j);
        float e0 = __shfl(e01, j), e1 = __shfl(e11, j);
        if (64 + j < cnt) {
          float4 v0 = ((const float4*)(z0 + (size_t)c * 64))[li];
          float4 v1 = ((const float4*)(z1 + (size_t)c * 64))[li];
          a0.x += e0 * v0.x; a0.y += e0 * v0.y; a0.z += e0 * v0.z; a0.w += e0 * v0.w;
          a1.x += e1 * v1.x; a1.y += e1 * v1.y; a1.z += e1 * v1.z; a1.w += e1 * v1.w;
        }
      }
    }
    grp_reduce(a0); grp_reduce(a1);
    if (g == 0) {
      float4 o;
      o.x = tanhf(0.5f * (a0.x * inv0 + a1.x * inv1));
      o.y = tanhf(0.5f * (a0.y * inv0 + a1.y * inv1));
      o.z = tanhf(0.5f * (a0.z * inv0 + a1.z * inv1));
      o.w = tanhf(0.5f * (a0.w * inv0 + a1.w * inv1));
      ((float4*)(aggs + ((size_t)row * 2 + 0) * 64))[li] = o;
    }
    return;
  }
  // ---------------- a2 path: 8 waves; lane-ownership matched to gather spans --------
  int row = blockIdx.x;
  int b = row >> 11;
  int cnt = a2_cnt[row];
  const int* idx = a2_idx + (size_t)row * A2_CAP;
  float2 ss = ((const float2*)ssrc2)[row];
  const float2* sd = (const float2*)sdst2 + (size_t)b * N_;
  // phase 1: lane owns tA = w*32 + (lane&31) + (lane>>5)*256 and tB = tA + 512
  int tA = w * 32 + (lane & 31) + (lane >> 5) * 256;
  int tB = tA + 512;
  int colA = 0, colB = 0;
  float eA0 = 0.f, eA1 = 0.f, eB0 = 0.f, eB1 = 0.f;
  float s0 = 0.f, s1 = 0.f;
  if (tA < cnt) {
    colA = idx[tA]; float2 s = sd[colA];
    eA0 = __expf(tanhf(ss.x + s.x)); eA1 = __expf(tanhf(ss.y + s.y));
    s0 += eA0; s1 += eA1;
  }
  if (tB < cnt) {
    colB = idx[tB]; float2 s = sd[colB];
    eB0 = __expf(tanhf(ss.x + s.x)); eB1 = __expf(tanhf(ss.y + s.y));
    s0 += eB0; s1 += eB1;
  }
  s0 = wave_sum(s0); s1 = wave_sum(s1);
  __shared__ float RED[2][8];
  __shared__ float WS0[8][64], WS1[8][64];
  if (lane == 0) { RED[0][w] = s0; RED[1][w] = s1; }
  const float* z0 = z + (size_t)b * N_ * 64;
  const float* z1 = z + ((size_t)(B_ * N_) + b * N_) * 64;
  int g = lane >> 4, li = lane & 15;
  float4 a0 = {0.f, 0.f, 0.f, 0.f}, a1 = {0.f, 0.f, 0.f, 0.f};
  #pragma unroll
  for (int pass = 0; pass < 4; pass++) {  // (A,h0) (A,h1) (B,h0) (B,h1)
    int half = pass & 1;
    int tbase = (pass >> 1) * 512 + half * 256 + w * 32;
    if (tbase >= cnt) continue;
    for (int j0 = 0; j0 < 32; j0 += 4) {
      if (tbase + j0 >= cnt) break;
      int j = j0 + g;
      int srcl = half * 32 + j;
      int col; float e0, e1;
      if (pass < 2) {
        col = __shfl(colA, srcl); e0 = __shfl(eA0, srcl); e1 = __shfl(eA1, srcl);
      } else {
        col = __shfl(colB, srcl); e0 = __shfl(eB0, srcl); e1 = __shfl(eB1, srcl);
      }
      if (tbase + j < cnt) {
        float4 v0 = ((const float4*)(z0 + (size_t)col * 64))[li];
        float4 v1 = ((const float4*)(z1 + (size_t)col * 64))[li];
        a0.x += e0 * v0.x; a0.y += e0 * v0.y; a0.z += e0 * v0.z; a0.w += e0 * v0.w;
        a1.x += e1 * v1.x; a1.y += e1 * v1.y; a1.z += e1 * v1.z; a1.w += e1 * v1.w;
      }
    }
  }
  grp_reduce(a0); grp_reduce(a1);
  if (g == 0) {
    ((float4*)WS0[w])[li] = a0;
    ((float4*)WS1[w])[li] = a1;
  }
  __syncthreads();
  if (tid < 64) {
    float tot0 = 0.f, tot1 = 0.f, r0 = 0.f, r1 = 0.f;
    #pragma unroll
    for (int q = 0; q < 8; q++) {
      tot0 += RED[0][q]; tot1 += RED[1][q];
      r0 += WS0[q][tid]; r1 += WS1[q][tid];
    }
    float inv0 = (tot0 > 0.f) ? 1.f / tot0 : 0.f;
    float inv1 = (tot1 > 0.f) ? 1.f / tot1 : 0.f;
    aggs[((size_t)row * 2 + 1) * 64 + tid] = tanhf(0.5f * (r0 * inv0 + r1 * inv1));
  }
}

// ---------------- nbr-softmax combine + GRU: direct weight loads, no arrays ---------
__global__ __launch_bounds__(256) void k_comb(
    const float* __restrict__ aggs, const float* __restrict__ nbr_q,
    const float* __restrict__ gru_W, const float* __restrict__ gru_U,
    const float* __restrict__ gru_b, float* __restrict__ h) {
  int tid = threadIdx.x, w = tid >> 6, j = tid & 63;
  int row0 = blockIdx.x * DR;
  __shared__ float HL[DR][64], NL[DR][64], RGL[DR][64];
  for (int t = tid; t < DR * 64; t += 256) HL[t >> 6][t & 63] = h[(size_t)row0 * 64 + t];
  float q = nbr_q[j];
  #pragma unroll
  for (int r = 0; r < 4; r++) {
    int rr = w * 4 + r, row = row0 + rr;
    float a0 = aggs[((size_t)row * 2 + 0) * 64 + j];
    float a1 = aggs[((size_t)row * 2 + 1) * 64 + j];
    float t0 = tanhf(wave_sum(a0 * q));
    float t1 = tanhf(wave_sum(a1 * q));
    float mx = fmaxf(t0, t1);
    float e0 = __expf(t0 - mx), e1 = __expf(t1 - mx);
    float inv = 1.f / (e0 + e1);
    NL[rr][j] = (e0 * a0 + e1 * a1) * inv;
  }
  __syncthreads();  // HL staging; NL/RGL rows are same-wave
  float az[4], ar[4];
  float bz = gru_b[j], br = gru_b[64 + j];
  #pragma unroll
  for (int r = 0; r < 4; r++) { az[r] = bz; ar[r] = br; }
  for (int dq = 0; dq < 16; dq++) {
    int d0 = 4 * dq;
    float wz0 = gru_W[(d0 + 0) * 192 + j],      wz1 = gru_W[(d0 + 1) * 192 + j];
    float wz2 = gru_W[(d0 + 2) * 192 + j],      wz3 = gru_W[(d0 + 3) * 192 + j];
    float wr0 = gru_W[(d0 + 0) * 192 + 64 + j], wr1 = gru_W[(d0 + 1) * 192 + 64 + j];
    float wr2 = gru_W[(d0 + 2) * 192 + 64 + j], wr3 = gru_W[(d0 + 3) * 192 + 64 + j];
    float uz0 = gru_U[(d0 + 0) * 192 + j],      uz1 = gru_U[(d0 + 1) * 192 + j];
    float uz2 = gru_U[(d0 + 2) * 192 + j],      uz3 = gru_U[(d0 + 3) * 192 + j];
    float ur0 = gru_U[(d0 + 0) * 192 + 64 + j], ur1 = gru_U[(d0 + 1) * 192 + 64 + j];
    float ur2 = gru_U[(d0 + 2) * 192 + 64 + j], ur3 = gru_U[(d0 + 3) * 192 + 64 + j];
    #pragma unroll
    for (int r = 0; r < 4; r++) {
      float4 n = ((const float4*)NL[w * 4 + r])[dq];
      float4 x = ((const float4*)HL[w * 4 + r])[dq];
      az[r] += n.x * wz0 + n.y * wz1 + n.z * wz2 + n.w * wz3
             + x.x * uz0 + x.y * uz1 + x.z * uz2 + x.w * uz3;
      ar[r] += n.x * wr0 + n.y * wr1 + n.z * wr2 + n.w * wr3
             + x.x * ur0 + x.y * ur1 + x.z * ur2 + x.w * ur3;
    }
  }
  float zgr[4];
  #pragma unroll
  for (int r = 0; r < 4; r++) {
    zgr[r] = 1.f / (1.f + __expf(-az[r]));
    RGL[w * 4 + r][j] = 1.f / (1.f + __expf(-ar[r]));  // same-wave rows
  }
  float ah[4];
  float bh = gru_b[128 + j];
  #pragma unroll
  for (int r = 0; r < 4; r++) ah[r] = bh;
  for (int dq = 0; dq < 16; dq++) {
    int d0 = 4 * dq;
    float wh0 = gru_W[(d0 + 0) * 192 + 128 + j], wh1 = gru_W[(d0 + 1) * 192 + 128 + j];
    float wh2 = gru_W[(d0 + 2) * 192 + 128 + j], wh3 = gru_W[(d0 + 3) * 192 + 128 + j];
    float uh0 = gru_U[(d0 + 0) * 192 + 128 + j], uh1 = gru_U[(d0 + 1) * 192 + 128 + j];
    float uh2 = gru_U[(d0 + 2) * 192 + 128 + j], uh3 = gru_U[(d0 + 3) * 192 + 128 + j];
    #pragma unroll
    for (int r = 0; r < 4; r++) {
      float4 n = ((const float4*)NL[w * 4 + r])[dq];
      float4 x = ((const float4*)HL[w * 4 + r])[dq];
      float4 rg = ((const float4*)RGL[w * 4 + r])[dq];
      ah[r] += n.x * wh0 + n.y * wh1 + n.z * wh2 + n.w * wh3
             + rg.x * x.x * uh0 + rg.y * x.y * uh1
             + rg.z * x.z * uh2 + rg.w * x.w * uh3;
    }
  }
  #pragma unroll
  for (int r = 0; r < 4; r++) {
    int rr = w * 4 + r;
    float ht = tanhf(ah[r]);
    float hj = HL[rr][j];
    h[(size_t)(row0 + rr) * 64 + j] = (1.f - zgr[r]) * hj + zgr[r] * ht;
  }
}

// ---------------- decoder + dual heads: direct weight loads ----------------
__global__ __launch_bounds__(256) void k_dec(
    const float* __restrict__ h, const float* __restrict__ dW0,
    const float* __restrict__ db0, const float* __restrict__ dW1,
    const float* __restrict__ db1, const float* __restrict__ uW0,
    const float* __restrict__ ub0, const float* __restrict__ uW1,
    const float* __restrict__ ub1, const float* __restrict__ demands,
    float* __restrict__ nw, float* __restrict__ dv, float* accum) {
  int tid = threadIdx.x, w = tid >> 6, j = tid & 63;
  int row0 = blockIdx.x * DR;
  __shared__ float HL[DR][64];
  __shared__ float DD[4];
  for (int t = tid; t < DR * 64; t += 256) HL[t >> 6][t & 63] = h[(size_t)row0 * 64 + t];
  __syncthreads();
  float accd[4], accu[4];
  float db0j = db0[j], ub0j = ub0[j];
  #pragma unroll
  for (int r = 0; r < 4; r++) { accd[r] = db0j; accu[r] = ub0j; }
  for (int dq = 0; dq < 16; dq++) {
    int d0 = 4 * dq;
    float dw0 = dW0[(d0 + 0) * 64 + j], dw1 = dW0[(d0 + 1) * 64 + j];
    float dw2 = dW0[(d0 + 2) * 64 + j], dw3 = dW0[(d0 + 3) * 64 + j];
    float uw0 = uW0[(d0 + 0) * 64 + j], uw1 = uW0[(d0 + 1) * 64 + j];
    float uw2 = uW0[(d0 + 2) * 64 + j], uw3 = uW0[(d0 + 3) * 64 + j];
    #pragma unroll
    for (int r = 0; r < 4; r++) {
      float4 x = ((const float4*)HL[w * 4 + r])[dq];
      accd[r] += x.x * dw0 + x.y * dw1 + x.z * dw2 + x.w * dw3;
      accu[r] += x.x * uw0 + x.y * uw1 + x.z * uw2 + x.w * uw3;
    }
  }
  float dw1c = dW1[j], uw1c = uW1[j];
  float db1s = db1[0], ub1s = ub1[0];
  float ddl = 0.f;
  #pragma unroll
  for (int r = 0; r < 4; r++) {
    int row = row0 + w * 4 + r;
    float a = wave_sum(tanhf(accd[r]) * dw1c);
    float bb = wave_sum(tanhf(accu[r]) * uw1c);
    if (j == 0) {
      float dvv = bb + ub1s;
      nw[row] = a + db1s; dv[row] = dvv;
      ddl += dvv * demands[row];
    }
  }
  if (j == 0) DD[w] = ddl;
  __syncthreads();
  if (tid == 0) atomicAdd(&accum[4 + (row0 >> 11)], DD[0] + DD[1] + DD[2] + DD[3]);
}

// ---------------- fused: row-softmax P + transpose scatter + s_1 init ---------------
__global__ void k_propT(const int* __restrict__ adj_idx, const int* __restrict__ adj_cnt,
                        const float* __restrict__ nw, const float* __restrict__ demands,
                        float* __restrict__ Pval, int* __restrict__ tcnt,
                        int* __restrict__ tsrc, float* __restrict__ tval,
                        float* __restrict__ sA) {
  int row = blockIdx.x;
  int lane = threadIdx.x;
  int b = row >> 11;
  int base = b * N_;
  int cnt = adj_cnt[row];
  const int* idx = adj_idx + (size_t)row * ADJ_CAP;
  int c0 = (lane < cnt) ? idx[lane] : -1;
  int c1 = (lane + 64 < cnt) ? idx[lane + 64] : -1;
  float v0 = (c0 >= 0) ? nw[base + c0] : -1e30f;
  float v1 = (c1 >= 0) ? nw[base + c1] : -1e30f;
  float m = wave_max(fmaxf(v0, v1));
  float e0 = (c0 >= 0) ? __expf(v0 - m) : 0.f;
  float e1 = (c1 >= 0) ? __expf(v1 - m) : 0.f;
  float s = wave_sum(e0 + e1);
  float inv = (s > 0.f) ? 1.f / s : 0.f;
  float p0 = e0 * inv, p1 = e1 * inv;
  if (c0 >= 0) {
    Pval[(size_t)row * ADJ_CAP + lane] = p0;
    int col = base + c0;
    int pos = atomicAdd(&tcnt[col], 1);
    if (pos < ADJ_CAP) {
      tsrc[(size_t)col * ADJ_CAP + pos] = row;
      tval[(size_t)col * ADJ_CAP + pos] = p0;
    }
  }
  if (c1 >= 0) {
    Pval[(size_t)row * ADJ_CAP + lane + 64] = p1;
    int col = base + c1;
    int pos = atomicAdd(&tcnt[col], 1);
    if (pos < ADJ_CAP) {
      tsrc[(size_t)col * ADJ_CAP + pos] = row;
      tval[(size_t)col * ADJ_CAP + pos] = p1;
    }
  }
  if (lane == 0) sA[row] = fmaxf(-demands[row], 0.f);
}

// ---------------- one MCF iteration: s_out[j] = relu(sum_i P[i][j] s_in[i] - d[j]) ----
__global__ __launch_bounds__(256) void k_mcf_iter(
    const int* __restrict__ tcnt, const int* __restrict__ tsrc,
    const float* __restrict__ tval, const float* __restrict__ demands,
    const float* __restrict__ s_in, float* __restrict__ s_out) {
  int j = blockIdx.x * 256 + threadIdx.x;  // 0..B*N-1
  int cnt = tcnt[j];
  const int* src = tsrc + (size_t)j * ADJ_CAP;
  const float* val = tval + (size_t)j * ADJ_CAP;
  float c = 0.f;
  int c4 = cnt >> 2;
  for (int q = 0; q < c4; q++) {
    int4 s4 = ((const int4*)src)[q];
    float4 v4 = ((const float4*)val)[q];
    c += v4.x * s_in[s4.x] + v4.y * s_in[s4.y] + v4.z * s_in[s4.z] + v4.w * s_in[s4.w];
  }
  for (int t = c4 * 4; t < cnt; t++) c += val[t] * s_in[src[t]];
  s_out[j] = fmaxf(c - demands[j], 0.f);
}

// ---------------- flow cost + dual recurrence; 4 rows per wave (16-lane groups) -----
__global__ __launch_bounds__(256) void k_flowdual(
    const int* __restrict__ adj_idx, const int* __restrict__ adj_cnt,
    const float* __restrict__ Pval, const float* __restrict__ s,
    const float* __restrict__ dv, float* accum) {
  int tid = threadIdx.x;  // 256
  int lane = tid & 63, w = tid >> 6;
  int r16 = lane >> 4, e = lane & 15;
  int row = blockIdx.x * 16 + w * 4 + r16;  // grid = B*N/16; same batch per block
  int b = row >> 11, i = row & (N_ - 1);
  int cnt = adj_cnt[row];
  float si = s[row], dvi = dv[row];
  const int* idx = adj_idx + (size_t)row * ADJ_CAP;
  const float* pv = Pval + (size_t)row * ADJ_CAP;
  float fc = 0.f, dc = 0.f;
  for (int t = e; t < cnt; t += 16) {
    int j = idx[t];
    float f_ij = si * pv[t];
    const int* jidx = adj_idx + (size_t)(b * N_ + j) * ADJ_CAP;
    int jcnt = adj_cnt[b * N_ + j];
    int lo = 0, hi = jcnt, pos = -1;
    while (lo < hi) {
      int mid = (lo + hi) >> 1;
      int v = jidx[mid];
      if (v == i) { pos = mid; break; }
      if (v < i) lo = mid + 1; else hi = mid;
    }
    float f_ji = (pos >= 0) ? s[b * N_ + j] * Pval[(size_t)(b * N_ + j) * ADJ_CAP + pos] : 0.f;
    float fin = f_ij - fminf(f_ij, f_ji);
    fc += fin * fin;
    float dd = dvi - dv[b * N_ + j];
    float y = 0.f, m = 0.f;
    #pragma unroll
    for (int q = 0; q < 10; q++) {
      float g = 2.f * y - dd;
      m = 0.9f * m + g;
      y = fmaxf(y - 0.1f * m, 0.f);
    }
    dc += y * y - dd * y;
  }
  fc = wave_sum(fc); dc = wave_sum(dc);
  __shared__ float FB[4], DB[4];
  if (lane == 0) { FB[w] = fc; DB[w] = dc; }
  __syncthreads();
  if (tid == 0) {
    int bb = (blockIdx.x * 16) >> 11;
    atomicAdd(&accum[bb], FB[0] + FB[1] + FB[2] + FB[3]);
    atomicAdd(&accum[2 + bb], DB[0] + DB[1] + DB[2] + DB[3]);
  }
}

// ---------------- finalize ----------------
__global__ void k_fin(const float* accum, float* out) {
  int b = threadIdx.x;
  if (b < B_) out[b] = accum[b] - accum[2 + b] + accum[4 + b];
}

extern "C" void kernel_launch(void* const* d_in, const int* in_sizes, int n_in,
                              void* d_out, int out_size, void* d_ws, size_t ws_size,
                              hipStream_t stream) {
  const float* feat    = (const float*)d_in[0];
  const float* emb     = (const float*)d_in[1];
  const float* demands = (const float*)d_in[2];
  // d_in[3] (adj) == neighborhoods[0]; not read.
  const float* nbhd    = (const float*)d_in[4];
  const float* enc_W0  = (const float*)d_in[5];
  const float* enc_b0  = (const float*)d_in[6];
  const float* enc_W1  = (const float*)d_in[7];
  const float* enc_b1  = (const float*)d_in[8];
  const float* attn_W  = (const float*)d_in[9];
  const float* a_src   = (const float*)d_in[10];
  const float* a_dst   = (const float*)d_in[11];
  const float* nbr_q   = (const float*)d_in[12];
  const float* gru_W   = (const float*)d_in[13];
  const float* gru_U   = (const float*)d_in[14];
  const float* gru_b   = (const float*)d_in[15];
  const float* dec_W0  = (const float*)d_in[16];
  const float* dec_b0  = (const float*)d_in[17];
  const float* dec_W1  = (const float*)d_in[18];
  const float* dec_b1  = (const float*)d_in[19];
  const float* dual_W0 = (const float*)d_in[20];
  const float* dual_b0 = (const float*)d_in[21];
  const float* dual_W1 = (const float*)d_in[22];
  const float* dual_b1 = (const float*)d_in[23];
  float* out = (float*)d_out;

  char* ws = (char*)d_ws;
  size_t off = 0;
  auto alloc = [&](size_t bytes) { char* p = ws + off; off += (bytes + 255) & ~(size_t)255; return p; };
  int*      adj_idx = (int*)     alloc((size_t)B_ * N_ * ADJ_CAP * 4);
  int*      adj_cnt = (int*)     alloc((size_t)B_ * N_ * 4);
  unsigned* amask   = (unsigned*)alloc((size_t)B_ * N_ * 64 * 4);
  int*      a2_idx  = (int*)     alloc((size_t)B_ * N_ * A2_CAP * 4);
  int*      a2_cnt  = (int*)     alloc((size_t)B_ * N_ * 4);
  float*    h       = (float*)   alloc((size_t)B_ * N_ * 64 * 4);
  float*    z       = (float*)   alloc((size_t)2 * B_ * N_ * 64 * 4);
  float*    ssrc2   = (float*)   alloc((size_t)2 * B_ * N_ * 4);
  float*    sdst2   = (float*)   alloc((size_t)2 * B_ * N_ * 4);
  float*    aggs    = (float*)   alloc((size_t)B_ * N_ * 2 * 64 * 4);
  float*    nw      = (float*)   alloc((size_t)B_ * N_ * 4);
  float*    dv      = (float*)   alloc((size_t)B_ * N_ * 4);
  float*    Pval    = (float*)   alloc((size_t)B_ * N_ * ADJ_CAP * 4);
  int*      tcnt    = (int*)     alloc((size_t)B_ * N_ * 4);
  int*      tsrc    = (int*)     alloc((size_t)B_ * N_ * ADJ_CAP * 4);
  float*    tval    = (float*)   alloc((size_t)B_ * N_ * ADJ_CAP * 4);
  float*    sA      = (float*)   alloc((size_t)B_ * N_ * 4);
  float*    sB      = (float*)   alloc((size_t)B_ * N_ * 4);
  float*    accum   = (float*)   alloc(8 * 4);

  k_csr_adj<<<(B_ * N_) / 4, 256, 0, stream>>>(nbhd, adj_idx, adj_cnt, amask, accum, tcnt);
  k_a2<<<B_ * N_, 64, 0, stream>>>(adj_idx, adj_cnt, amask, a2_idx, a2_cnt);
  k_enc<<<(B_ * N_) / DR, 256, 0, stream>>>(emb, feat, enc_W0, enc_b0, enc_W1, enc_b1, h);
  for (int layer = 0; layer < 2; layer++) {
    k_z<<<(B_ * N_) / DR, 256, 0, stream>>>(h, attn_W, a_src, a_dst, z, ssrc2, sdst2);
    k_agg<<<2 * B_ * N_, 512, 0, stream>>>(adj_idx, adj_cnt, a2_idx, a2_cnt,
                                           z, ssrc2, sdst2, aggs);
    k_comb<<<(B_ * N_) / DR, 256, 0, stream>>>(aggs, nbr_q, gru_W, gru_U, gru_b, h);
  }
  k_dec<<<(B_ * N_) / DR, 256, 0, stream>>>(h, dec_W0, dec_b0, dec_W1, dec_b1,
                                            dual_W0, dual_b0, dual_W1, dual_b1,
                                            demands, nw, dv, accum);
  k_propT<<<B_ * N_, 64, 0, stream>>>(adj_idx, adj_cnt, nw, demands, Pval,
                                      tcnt, tsrc, tval, sA);
  // s_1 = relu(-d) in sA; 9 more iterations -> s_10 ends in sB
  for (int it = 0; it < 9; it++) {
    float* sin  = (it & 1) ? sB : sA;
    float* sout = (it & 1) ? sA : sB;
    k_mcf_iter<<<(B_ * N_) / 256, 256, 0, stream>>>(tcnt, tsrc, tval, demands, sin, sout);
  }
  k_flowdual<<<(B_ * N_) / 16, 256, 0, stream>>>(adj_idx, adj_cnt, Pval, sB, dv, accum);
  k_fin<<<1, 64, 0, stream>>>(accum, out);
}